// Round 17
// baseline (84.121 us; speedup 1.0000x reference)
//
#include <hip/hip_runtime.h>
#include <hip/hip_bf16.h>

#define SIZE 6144
#define DDIM 2048
#define BHALF 2048
#define BIJ 4096
#define NT 48   // 6144 / 128 tiles per dim

typedef __attribute__((ext_vector_type(4))) float f32x4;
typedef __attribute__((ext_vector_type(4))) int i32x4;
typedef __attribute__((ext_vector_type(8))) int i32x8;

__device__ __forceinline__ float block_reduce_sum(float v, float* red) {
    #pragma unroll
    for (int off = 32; off; off >>= 1) v += __shfl_xor(v, off, 64);
    int lane = threadIdx.x & 63, wid = threadIdx.x >> 6;
    if (lane == 0) red[wid] = v;
    __syncthreads();
    float t = red[0] + red[1] + red[2] + red[3];
    __syncthreads();
    return t;
}

// Round-to-nearest e2m1 quantize via the half-ULP bit trick (1-bit mantissa):
// grid {0,.5,1,1.5,2,3,4,6}. Verified on boundaries: 1.5, 6.0, binade carries.
__device__ __forceinline__ void quant_e2m1(float xv, unsigned int& code, float& dec) {
    float ax = fabsf(xv);
    float y  = fminf(fmaxf(ax, 1.0f), 6.0f);
    unsigned int u = (__float_as_uint(y) + 0x00200000u) & 0xFFC00000u;
    float dh = __uint_as_float(u);
    unsigned int m  = (u >> 22) & 1u;
    unsigned int e  = ((u >> 23) & 0xFFu) - 127u;   // 0..2
    unsigned int ch = ((e + 1u) << 1) | m;          // 2..7
    bool lo = ax < 0.75f, z = ax < 0.25f;
    dec  = lo ? (z ? 0.f : 0.5f) : dh;
    code = (lo ? (z ? 0u : 1u) : ch) | (xv < 0.f ? 8u : 0u);
}

// One block (256 thr) per row: L2-normalize in fp32, quantize z*64 to fp4
// e2m1 (2/byte, row pitch 1024 B), dii[r] = ||z_q||^2/4096 from the SAME
// quantized values (diagonal exp cancels exactly). Blocks 0..47 zero S;
// block 0 zeroes the completion counter (graph-replay deterministic).
__global__ __launch_bounds__(256) void normalize_kernel(
    const float* __restrict__ ei, const float* __restrict__ ej,
    const float* __restrict__ ek,
    unsigned char* __restrict__ zb4, float* __restrict__ dii,
    float* __restrict__ S, unsigned int* __restrict__ cnt)
{
    __shared__ float red[4];
    int r = blockIdx.x;
    if (r < 48) S[r * 256 + threadIdx.x] = 0.f;   // 48*256 = 2*SIZE
    if (r == 0 && threadIdx.x == 0) *cnt = 0u;
    const float* src = (r < BHALF)   ? (ei + (size_t)r * DDIM)
                     : (r < 2*BHALF) ? (ej + (size_t)(r - BHALF) * DDIM)
                                     : (ek + (size_t)(r - 2*BHALF) * DDIM);
    int t = threadIdx.x;
    float4 v0 = ((const float4*)src)[t*2];
    float4 v1 = ((const float4*)src)[t*2 + 1];
    float ss = v0.x*v0.x + v0.y*v0.y + v0.z*v0.z + v0.w*v0.w
             + v1.x*v1.x + v1.y*v1.y + v1.z*v1.z + v1.w*v1.w;
    float tot = block_reduce_sum(ss, red);
    float scale = 64.0f / fmaxf(sqrtf(tot), 1e-12f);   // z * 64

    float xs[8] = {v0.x, v0.y, v0.z, v0.w, v1.x, v1.y, v1.z, v1.w};
    unsigned int pk = 0;
    float d = 0.f;
    #pragma unroll
    for (int jj = 0; jj < 8; ++jj) {
        unsigned int c; float dec;
        quant_e2m1(xs[jj] * scale, c, dec);
        d += dec * dec;
        pk |= c << (4 * jj);
    }
    ((unsigned int*)zb4)[(size_t)r * 256 + t] = pk;   // row pitch 1024 B
    float dtot = block_reduce_sum(d, red);
    if (t == 0) dii[r] = dtot * (1.0f / 4096.0f);
}

// Symmetric simexp, MX-fp4, LDS-staged, R14-verified depth-1 prefetch
// skeleton (best of 6 schedule variants this session), PLUS fused loss:
// the last block to finish (device counter) computes the final scalar.
//   - tile 128x128, BK=128 fp4, 16 K-iters; LDS 2x(8+8) KiB = 32768 B
//     -> EXACTLY 5 blocks/CU (160 KiB / 32 KiB); VGPR must stay <= 102
//   - stage next K-tile (4 loads/wave) BEFORE consuming current; ONE
//     __syncthreads per iter (drain lands after the compute)
//   - swizzle: lane l stages chunk ((l&3)^((row>>1)&3)) of its row's 64B
//     window (full-line coalescing); reads slot l4^((lr>>1)&3) (conflict-free)
//   - mfma_scale_f32_16x16x128_f8f6f4 cbsz=blgp=4, scales 0x79 (exact /4096)
//   - fused loss coherency (G16): release = per-block __syncthreads vmcnt
//     drain + __threadfence before cnt RMW; acquire = __threadfence after
//     winning RMW + __hip_atomic_load(AGENT) reads of S (bypasses the
//     non-coherent per-XCD L2s). Shared flag/reduce reuse As (LDS unchanged).
__global__ __launch_bounds__(256) void simexp_kernel(
    const unsigned char* __restrict__ zb4, float* __restrict__ S,
    const float* __restrict__ dii, unsigned int* __restrict__ cnt,
    float* __restrict__ out)
{
    __shared__ unsigned char As[2][8192];
    __shared__ unsigned char Bs[2][8192];

    const int x  = blockIdx.x & 7;
    const int j  = blockIdx.x >> 3;
    const int pi = j / 49;
    const int jj = j % 49;
    const int p  = 3 * x + pi;
    int rt, ct;
    if (jj < 48 - p) { rt = p;      ct = p + jj; }
    else             { rt = 47 - p; ct = rt + (jj - (48 - p)); }

    const int tid  = threadIdx.x;
    const int lane = tid & 63;
    const int w    = tid >> 6;       // wave 0..3
    const int wr   = w >> 1, wc = w & 1;
    const int rowA0 = rt * 128, colB0 = ct * 128;

    const int rowc = lane >> 2;                               // 0..15
    const int csw  = (((lane & 3) ^ ((rowc >> 1) & 3))) * 16; // swizzled chunk (bytes)

    const int lr = lane & 15;
    const int l4 = lane >> 4;                                 // 0..3
    const int rsl = ((l4 ^ ((lr >> 1) & 3))) * 16;            // read slot (bytes)

    f32x4 acc[4][4] = {};

    // staging duty: wave w covers 16-row groups {2w, 2w+1} of A and B
#define STAGE(buf, kw) do {                                                  \
    _Pragma("unroll")                                                        \
    for (int g2 = 0; g2 < 2; ++g2) {                                         \
        const int g = w * 2 + g2;                                            \
        const unsigned char* ga = zb4                                        \
            + (size_t)(rowA0 + g*16 + rowc) * 1024 + (kw)*64 + csw;          \
        __builtin_amdgcn_global_load_lds(                                    \
            (const __attribute__((address_space(1))) void*)ga,               \
            (__attribute__((address_space(3))) void*)&As[buf][g * 1024],     \
            16, 0, 0);                                                       \
        const unsigned char* gb = zb4                                        \
            + (size_t)(colB0 + g*16 + rowc) * 1024 + (kw)*64 + csw;          \
        __builtin_amdgcn_global_load_lds(                                    \
            (const __attribute__((address_space(1))) void*)gb,               \
            (__attribute__((address_space(3))) void*)&Bs[buf][g * 1024],     \
            16, 0, 0);                                                       \
    }                                                                        \
} while (0)

    STAGE(0, 0);
    __syncthreads();

    for (int t = 0; t < 16; ++t) {
        const int cur = t & 1;
        if (t < 15) STAGE(cur ^ 1, t + 1);   // prefetch next K-tile

        i32x8 a8[4];
        #pragma unroll
        for (int mi = 0; mi < 4; ++mi) {
            i32x4 tv = *(const i32x4*)&As[cur][(wr*4 + mi)*1024 + lr*64 + rsl];
            a8[mi] = __builtin_shufflevector(tv, tv, 0, 1, 2, 3, -1, -1, -1, -1);
        }
        __builtin_amdgcn_s_setprio(1);
        #pragma unroll
        for (int ni = 0; ni < 4; ++ni) {
            i32x4 tv = *(const i32x4*)&Bs[cur][(wc*4 + ni)*1024 + lr*64 + rsl];
            i32x8 b8 = __builtin_shufflevector(tv, tv, 0, 1, 2, 3, -1, -1, -1, -1);
            #pragma unroll
            for (int mi = 0; mi < 4; ++mi)
                acc[mi][ni] = __builtin_amdgcn_mfma_scale_f32_16x16x128_f8f6f4(
                    a8[mi], b8, acc[mi][ni], 4, 4,
                    0, 0x79797979, 0, 0x79797979);
        }
        __builtin_amdgcn_s_setprio(0);

        if (t < 15) __syncthreads();   // drains vmcnt+lgkm: next buf ready,
                                       // current buf safe to overwrite
    }

    // exp in-register (reused for both row- and col-sums)
    #pragma unroll
    for (int mi = 0; mi < 4; ++mi)
        #pragma unroll
        for (int ni = 0; ni < 4; ++ni)
            #pragma unroll
            for (int q = 0; q < 4; ++q)
                acc[mi][ni][q] = __expf(10.0f * acc[mi][ni][q]);

    // ---- row-sums: C/D row = (lane>>4)*4 + q (+mi*16), col = lane&15 (+ni*16)
    {
        float rs[4][4];
        #pragma unroll
        for (int mi = 0; mi < 4; ++mi)
            #pragma unroll
            for (int q = 0; q < 4; ++q) {
                float s = 0.f;
                #pragma unroll
                for (int ni = 0; ni < 4; ++ni) s += acc[mi][ni][q];
                rs[mi][q] = s;
            }
        #pragma unroll
        for (int off = 1; off < 16; off <<= 1)
            #pragma unroll
            for (int mi = 0; mi < 4; ++mi)
                #pragma unroll
                for (int q = 0; q < 4; ++q)
                    rs[mi][q] += __shfl_xor(rs[mi][q], off, 64);

        if ((lane & 15) == 0) {
            float* St = S + ((ct < BIJ / 128) ? 0 : SIZE);
            int rq = l4 * 4;
            #pragma unroll
            for (int mi = 0; mi < 4; ++mi)
                #pragma unroll
                for (int q = 0; q < 4; ++q)
                    atomicAdd(&St[rowA0 + wr*64 + mi*16 + rq + q], rs[mi][q]);
        }
    }

    // ---- col-sums (transpose contribution), off-diagonal tiles only
    if (rt != ct) {
        float cs[4];
        #pragma unroll
        for (int ni = 0; ni < 4; ++ni) {
            float s = 0.f;
            #pragma unroll
            for (int mi = 0; mi < 4; ++mi)
                #pragma unroll
                for (int q = 0; q < 4; ++q) s += acc[mi][ni][q];
            cs[ni] = s;
        }
        #pragma unroll
        for (int off = 16; off < 64; off <<= 1)
            #pragma unroll
            for (int ni = 0; ni < 4; ++ni)
                cs[ni] += __shfl_xor(cs[ni], off, 64);

        if (lane < 16) {
            float* St = S + ((rt < BIJ / 128) ? 0 : SIZE);
            #pragma unroll
            for (int ni = 0; ni < 4; ++ni)
                atomicAdd(&St[colB0 + wc*64 + ni*16 + lane], cs[ni]);
        }
    }

    // ---- fused loss: last block to finish computes the scalar.
    __syncthreads();          // all this block's S atomics issued+drained (vmcnt0)
    unsigned int* flag = (unsigned int*)&As[0][0];   // LDS reuse (post-barrier)
    float* red = (float*)&As[0][64];
    if (tid == 0) {
        __threadfence();      // release: S updates visible before cnt RMW
        unsigned int old = atomicAdd(cnt, 1u);
        *flag = (old == (unsigned int)(NT * (NT + 1) / 2 - 1)) ? 1u : 0u;
    }
    __syncthreads();
    if (*flag) {
        __threadfence();      // acquire side
        float local = 0.f;
        const float c1 = logf((float)(BIJ - 1));
        const float c2 = logf((float)(BHALF - 1));
        for (int r = tid; r < SIZE; r += 256) {
            float s1 = __hip_atomic_load(&S[r], __ATOMIC_RELAXED,
                                         __HIP_MEMORY_SCOPE_AGENT);
            float s2 = __hip_atomic_load(&S[SIZE + r], __ATOMIC_RELAXED,
                                         __HIP_MEMORY_SCOPE_AGENT);
            float eii = __expf(10.0f * dii[r]);
            float denom = s1 + s2 - eii;
            float num, c;
            if (r < BIJ) { num = s1 - eii; c = c1; }
            else         { num = s2 - eii; c = c2; }
            local += __logf(denom / num) + c;
        }
        float tot = block_reduce_sum(local, red);
        if (tid == 0) out[0] = tot / (float)SIZE;
    }
}

extern "C" void kernel_launch(void* const* d_in, const int* in_sizes, int n_in,
                              void* d_out, int out_size, void* d_ws, size_t ws_size,
                              hipStream_t stream) {
    const float* ei = (const float*)d_in[0];
    const float* ej = (const float*)d_in[1];
    const float* ek = (const float*)d_in[2];
    float* out = (float*)d_out;

    char* ws = (char*)d_ws;
    unsigned char* zb4 = (unsigned char*)ws;                     // 6144*1024 = 6291456 B
    float* dii = (float*)(ws + 6291456);                         // 24576 B
    float* S   = (float*)(ws + 6291456 + 24576);                 // 2*6144*4 = 49152 B
    unsigned int* cnt = (unsigned int*)(ws + 6291456 + 24576 + 49152); // 4 B

    normalize_kernel<<<dim3(SIZE), dim3(256), 0, stream>>>(ei, ej, ek, zb4, dii, S, cnt);
    simexp_kernel<<<dim3(NT * (NT + 1) / 2), dim3(256), 0, stream>>>(zb4, S, dii, cnt, out);
}

// Round 18
// 69.838 us; speedup vs baseline: 1.2045x; 1.2045x over previous
//
#include <hip/hip_runtime.h>
#include <hip/hip_bf16.h>

#define SIZE 6144
#define DDIM 2048
#define BHALF 2048
#define BIJ 4096
#define NT 48   // 6144 / 128 tiles per dim

typedef __attribute__((ext_vector_type(4))) float f32x4;
typedef __attribute__((ext_vector_type(4))) int i32x4;
typedef __attribute__((ext_vector_type(8))) int i32x8;

__device__ __forceinline__ float block_reduce_sum(float v, float* red) {
    #pragma unroll
    for (int off = 32; off; off >>= 1) v += __shfl_xor(v, off, 64);
    int lane = threadIdx.x & 63, wid = threadIdx.x >> 6;
    if (lane == 0) red[wid] = v;
    __syncthreads();
    float t = red[0] + red[1] + red[2] + red[3];
    __syncthreads();
    return t;
}

// Round-to-nearest e2m1 quantize via the half-ULP bit trick (1-bit mantissa):
// grid {0,.5,1,1.5,2,3,4,6}. Verified on boundaries: 1.5, 6.0, binade carries.
__device__ __forceinline__ void quant_e2m1(float xv, unsigned int& code, float& dec) {
    float ax = fabsf(xv);
    float y  = fminf(fmaxf(ax, 1.0f), 6.0f);
    unsigned int u = (__float_as_uint(y) + 0x00200000u) & 0xFFC00000u;
    float dh = __uint_as_float(u);
    unsigned int m  = (u >> 22) & 1u;
    unsigned int e  = ((u >> 23) & 0xFFu) - 127u;   // 0..2
    unsigned int ch = ((e + 1u) << 1) | m;          // 2..7
    bool lo = ax < 0.75f, z = ax < 0.25f;
    dec  = lo ? (z ? 0.f : 0.5f) : dh;
    code = (lo ? (z ? 0u : 1u) : ch) | (xv < 0.f ? 8u : 0u);
}

// One block (256 thr) per row: L2-normalize in fp32, quantize z*64 to fp4
// e2m1 (2/byte, row pitch 1024 B), dii[r] = ||z_q||^2/4096 from the SAME
// quantized values (diagonal exp cancels exactly). Blocks 0..47 zero S.
__global__ __launch_bounds__(256) void normalize_kernel(
    const float* __restrict__ ei, const float* __restrict__ ej,
    const float* __restrict__ ek,
    unsigned char* __restrict__ zb4, float* __restrict__ dii,
    float* __restrict__ S)
{
    __shared__ float red[4];
    int r = blockIdx.x;
    if (r < 48) S[r * 256 + threadIdx.x] = 0.f;   // 48*256 = 2*SIZE
    const float* src = (r < BHALF)   ? (ei + (size_t)r * DDIM)
                     : (r < 2*BHALF) ? (ej + (size_t)(r - BHALF) * DDIM)
                                     : (ek + (size_t)(r - 2*BHALF) * DDIM);
    int t = threadIdx.x;
    float4 v0 = ((const float4*)src)[t*2];
    float4 v1 = ((const float4*)src)[t*2 + 1];
    float ss = v0.x*v0.x + v0.y*v0.y + v0.z*v0.z + v0.w*v0.w
             + v1.x*v1.x + v1.y*v1.y + v1.z*v1.z + v1.w*v1.w;
    float tot = block_reduce_sum(ss, red);
    float scale = 64.0f / fmaxf(sqrtf(tot), 1e-12f);   // z * 64

    float xs[8] = {v0.x, v0.y, v0.z, v0.w, v1.x, v1.y, v1.z, v1.w};
    unsigned int pk = 0;
    float d = 0.f;
    #pragma unroll
    for (int jj = 0; jj < 8; ++jj) {
        unsigned int c; float dec;
        quant_e2m1(xs[jj] * scale, c, dec);
        d += dec * dec;
        pk |= c << (4 * jj);
    }
    ((unsigned int*)zb4)[(size_t)r * 256 + t] = pk;   // row pitch 1024 B
    float dtot = block_reduce_sum(d, red);
    if (t == 0) dii[r] = dtot * (1.0f / 4096.0f);
}

// Symmetric simexp, MX-fp4, LDS-staged, R14-verified depth-1 prefetch
// skeleton (the best of 6 schedule variants tested in this session):
//   - tile 128x128, BK=128 fp4 (= 64 B/row window), 16 K-iters
//   - LDS 2 x (8 KiB A + 8 KiB B) = 32 KiB  -> ~5 blocks/CU (TLP is the
//     load-latency cover; every 1-2-block/CU variant lost more than it gained)
//   - stage next K-tile (4 loads/wave) BEFORE consuming current; ONE
//     __syncthreads per iter, whose vmcnt/lgkm drain lands after the compute
//   - staging: lane l covers row l>>2 (4 lanes = full 64B line, coalesced),
//     fetches chunk ((l&3) ^ ((row>>1)&3)); reads use slot l4^((lr>>1)&3)
//     -> 2 lanes/bank-group (free, measured-zero conflicts)
//   - mfma_scale_f32_16x16x128_f8f6f4 cbsz=blgp=4 (fp4), scales 0x79
//     (2^-6 each operand -> exact /4096 dequant of z*64)
// XCD-aware triangular decode (1176 = 8 XCDs x 147 jobs, balanced).
// NOTE (R17 lesson): do NOT fuse the loss pass here — per-block
// __threadfence for cross-workgroup visibility costs ~27 us (device-scope
// fence in 1176 blocks), far more than the saved launch gap.
__global__ __launch_bounds__(256) void simexp_kernel(
    const unsigned char* __restrict__ zb4, float* __restrict__ S)
{
    __shared__ unsigned char As[2][8192];
    __shared__ unsigned char Bs[2][8192];

    const int x  = blockIdx.x & 7;
    const int j  = blockIdx.x >> 3;
    const int pi = j / 49;
    const int jj = j % 49;
    const int p  = 3 * x + pi;
    int rt, ct;
    if (jj < 48 - p) { rt = p;      ct = p + jj; }
    else             { rt = 47 - p; ct = rt + (jj - (48 - p)); }

    const int tid  = threadIdx.x;
    const int lane = tid & 63;
    const int w    = tid >> 6;       // wave 0..3
    const int wr   = w >> 1, wc = w & 1;
    const int rowA0 = rt * 128, colB0 = ct * 128;

    const int rowc = lane >> 2;                               // 0..15
    const int csw  = (((lane & 3) ^ ((rowc >> 1) & 3))) * 16; // swizzled chunk (bytes)

    const int lr = lane & 15;
    const int l4 = lane >> 4;                                 // 0..3
    const int rsl = ((l4 ^ ((lr >> 1) & 3))) * 16;            // read slot (bytes)

    f32x4 acc[4][4] = {};

    // staging duty: wave w covers 16-row groups {2w, 2w+1} of A and B
#define STAGE(buf, kw) do {                                                  \
    _Pragma("unroll")                                                        \
    for (int g2 = 0; g2 < 2; ++g2) {                                         \
        const int g = w * 2 + g2;                                            \
        const unsigned char* ga = zb4                                        \
            + (size_t)(rowA0 + g*16 + rowc) * 1024 + (kw)*64 + csw;          \
        __builtin_amdgcn_global_load_lds(                                    \
            (const __attribute__((address_space(1))) void*)ga,               \
            (__attribute__((address_space(3))) void*)&As[buf][g * 1024],     \
            16, 0, 0);                                                       \
        const unsigned char* gb = zb4                                        \
            + (size_t)(colB0 + g*16 + rowc) * 1024 + (kw)*64 + csw;          \
        __builtin_amdgcn_global_load_lds(                                    \
            (const __attribute__((address_space(1))) void*)gb,               \
            (__attribute__((address_space(3))) void*)&Bs[buf][g * 1024],     \
            16, 0, 0);                                                       \
    }                                                                        \
} while (0)

    STAGE(0, 0);
    __syncthreads();

    for (int t = 0; t < 16; ++t) {
        const int cur = t & 1;
        if (t < 15) STAGE(cur ^ 1, t + 1);   // prefetch next K-tile

        i32x8 a8[4];
        #pragma unroll
        for (int mi = 0; mi < 4; ++mi) {
            i32x4 tv = *(const i32x4*)&As[cur][(wr*4 + mi)*1024 + lr*64 + rsl];
            a8[mi] = __builtin_shufflevector(tv, tv, 0, 1, 2, 3, -1, -1, -1, -1);
        }
        __builtin_amdgcn_s_setprio(1);
        #pragma unroll
        for (int ni = 0; ni < 4; ++ni) {
            i32x4 tv = *(const i32x4*)&Bs[cur][(wc*4 + ni)*1024 + lr*64 + rsl];
            i32x8 b8 = __builtin_shufflevector(tv, tv, 0, 1, 2, 3, -1, -1, -1, -1);
            #pragma unroll
            for (int mi = 0; mi < 4; ++mi)
                acc[mi][ni] = __builtin_amdgcn_mfma_scale_f32_16x16x128_f8f6f4(
                    a8[mi], b8, acc[mi][ni], 4, 4,
                    0, 0x79797979, 0, 0x79797979);
        }
        __builtin_amdgcn_s_setprio(0);

        if (t < 15) __syncthreads();   // drains vmcnt+lgkm: next buf ready,
                                       // current buf safe to overwrite
    }

    // exp in-register (reused for both row- and col-sums)
    #pragma unroll
    for (int mi = 0; mi < 4; ++mi)
        #pragma unroll
        for (int ni = 0; ni < 4; ++ni)
            #pragma unroll
            for (int q = 0; q < 4; ++q)
                acc[mi][ni][q] = __expf(10.0f * acc[mi][ni][q]);

    // ---- row-sums: C/D row = (lane>>4)*4 + q (+mi*16), col = lane&15 (+ni*16)
    {
        float rs[4][4];
        #pragma unroll
        for (int mi = 0; mi < 4; ++mi)
            #pragma unroll
            for (int q = 0; q < 4; ++q) {
                float s = 0.f;
                #pragma unroll
                for (int ni = 0; ni < 4; ++ni) s += acc[mi][ni][q];
                rs[mi][q] = s;
            }
        #pragma unroll
        for (int off = 1; off < 16; off <<= 1)
            #pragma unroll
            for (int mi = 0; mi < 4; ++mi)
                #pragma unroll
                for (int q = 0; q < 4; ++q)
                    rs[mi][q] += __shfl_xor(rs[mi][q], off, 64);

        if ((lane & 15) == 0) {
            float* St = S + ((ct < BIJ / 128) ? 0 : SIZE);
            int rq = l4 * 4;
            #pragma unroll
            for (int mi = 0; mi < 4; ++mi)
                #pragma unroll
                for (int q = 0; q < 4; ++q)
                    atomicAdd(&St[rowA0 + wr*64 + mi*16 + rq + q], rs[mi][q]);
        }
    }

    // ---- col-sums (transpose contribution), off-diagonal tiles only
    if (rt != ct) {
        float cs[4];
        #pragma unroll
        for (int ni = 0; ni < 4; ++ni) {
            float s = 0.f;
            #pragma unroll
            for (int mi = 0; mi < 4; ++mi)
                #pragma unroll
                for (int q = 0; q < 4; ++q) s += acc[mi][ni][q];
            cs[ni] = s;
        }
        #pragma unroll
        for (int off = 16; off < 64; off <<= 1)
            #pragma unroll
            for (int ni = 0; ni < 4; ++ni)
                cs[ni] += __shfl_xor(cs[ni], off, 64);

        if (lane < 16) {
            float* St = S + ((rt < BIJ / 128) ? 0 : SIZE);
            #pragma unroll
            for (int ni = 0; ni < 4; ++ni)
                atomicAdd(&St[colB0 + wc*64 + ni*16 + lane], cs[ni]);
        }
    }
}

// Single block: per-row loss terms, total, write scalar.
__global__ __launch_bounds__(256) void loss_kernel(
    const float* __restrict__ S, const float* __restrict__ dii,
    float* __restrict__ out)
{
    __shared__ float red[4];
    float local = 0.f;
    const float c1 = logf((float)(BIJ - 1));
    const float c2 = logf((float)(BHALF - 1));
    for (int r = threadIdx.x; r < SIZE; r += 256) {
        float s1 = S[r], s2 = S[SIZE + r];
        float eii = __expf(10.0f * dii[r]);
        float denom = s1 + s2 - eii;
        float num, c;
        if (r < BIJ) { num = s1 - eii; c = c1; }
        else         { num = s2 - eii; c = c2; }
        local += __logf(denom / num) + c;
    }
    float tot = block_reduce_sum(local, red);
    if (threadIdx.x == 0) out[0] = tot / (float)SIZE;
}

extern "C" void kernel_launch(void* const* d_in, const int* in_sizes, int n_in,
                              void* d_out, int out_size, void* d_ws, size_t ws_size,
                              hipStream_t stream) {
    const float* ei = (const float*)d_in[0];
    const float* ej = (const float*)d_in[1];
    const float* ek = (const float*)d_in[2];
    float* out = (float*)d_out;

    char* ws = (char*)d_ws;
    unsigned char* zb4 = (unsigned char*)ws;                     // 6144*1024 = 6291456 B
    float* dii = (float*)(ws + 6291456);                         // 24576 B
    float* S   = (float*)(ws + 6291456 + 24576);                 // 2*6144*4 = 49152 B

    normalize_kernel<<<dim3(SIZE), dim3(256), 0, stream>>>(ei, ej, ek, zb4, dii, S);
    simexp_kernel<<<dim3(NT * (NT + 1) / 2), dim3(256), 0, stream>>>(zb4, S);
    loss_kernel<<<dim3(1), dim3(256), 0, stream>>>(S, dii, out);
}

// Round 19
// 68.536 us; speedup vs baseline: 1.2274x; 1.0190x over previous
//
#include <hip/hip_runtime.h>
#include <hip/hip_bf16.h>

#define SIZE 6144
#define DDIM 2048
#define BHALF 2048
#define BIJ 4096
#define NT 48   // 6144 / 128 tiles per dim

typedef __attribute__((ext_vector_type(4))) float f32x4;
typedef __attribute__((ext_vector_type(4))) int i32x4;
typedef __attribute__((ext_vector_type(8))) int i32x8;

__device__ __forceinline__ float block_reduce_sum(float v, float* red) {
    #pragma unroll
    for (int off = 32; off; off >>= 1) v += __shfl_xor(v, off, 64);
    int lane = threadIdx.x & 63, wid = threadIdx.x >> 6;
    if (lane == 0) red[wid] = v;
    __syncthreads();
    float t = red[0] + red[1] + red[2] + red[3];
    __syncthreads();
    return t;
}

// Round-to-nearest e2m1 quantize via the half-ULP bit trick (1-bit mantissa):
// grid {0,.5,1,1.5,2,3,4,6}. Verified on boundaries: 1.5, 6.0, binade carries.
__device__ __forceinline__ void quant_e2m1(float xv, unsigned int& code, float& dec) {
    float ax = fabsf(xv);
    float y  = fminf(fmaxf(ax, 1.0f), 6.0f);
    unsigned int u = (__float_as_uint(y) + 0x00200000u) & 0xFFC00000u;
    float dh = __uint_as_float(u);
    unsigned int m  = (u >> 22) & 1u;
    unsigned int e  = ((u >> 23) & 0xFFu) - 127u;   // 0..2
    unsigned int ch = ((e + 1u) << 1) | m;          // 2..7
    bool lo = ax < 0.75f, z = ax < 0.25f;
    dec  = lo ? (z ? 0.f : 0.5f) : dh;
    code = (lo ? (z ? 0u : 1u) : ch) | (xv < 0.f ? 8u : 0u);
}

// One block (256 thr) per row: L2-normalize in fp32, quantize z*64 to fp4
// e2m1 (2/byte, row pitch 1024 B), dii[r] = ||z_q||^2/4096 from the SAME
// quantized values (diagonal exp cancels exactly). Blocks 0..47 zero S.
__global__ __launch_bounds__(256) void normalize_kernel(
    const float* __restrict__ ei, const float* __restrict__ ej,
    const float* __restrict__ ek,
    unsigned char* __restrict__ zb4, float* __restrict__ dii,
    float* __restrict__ S)
{
    __shared__ float red[4];
    int r = blockIdx.x;
    if (r < 48) S[r * 256 + threadIdx.x] = 0.f;   // 48*256 = 2*SIZE
    const float* src = (r < BHALF)   ? (ei + (size_t)r * DDIM)
                     : (r < 2*BHALF) ? (ej + (size_t)(r - BHALF) * DDIM)
                                     : (ek + (size_t)(r - 2*BHALF) * DDIM);
    int t = threadIdx.x;
    float4 v0 = ((const float4*)src)[t*2];
    float4 v1 = ((const float4*)src)[t*2 + 1];
    float ss = v0.x*v0.x + v0.y*v0.y + v0.z*v0.z + v0.w*v0.w
             + v1.x*v1.x + v1.y*v1.y + v1.z*v1.z + v1.w*v1.w;
    float tot = block_reduce_sum(ss, red);
    float scale = 64.0f / fmaxf(sqrtf(tot), 1e-12f);   // z * 64

    float xs[8] = {v0.x, v0.y, v0.z, v0.w, v1.x, v1.y, v1.z, v1.w};
    unsigned int pk = 0;
    float d = 0.f;
    #pragma unroll
    for (int jj = 0; jj < 8; ++jj) {
        unsigned int c; float dec;
        quant_e2m1(xs[jj] * scale, c, dec);
        d += dec * dec;
        pk |= c << (4 * jj);
    }
    ((unsigned int*)zb4)[(size_t)r * 256 + t] = pk;   // row pitch 1024 B
    float dtot = block_reduce_sum(d, red);
    if (t == 0) dii[r] = dtot * (1.0f / 4096.0f);
}

// Symmetric simexp, MX-fp4, LDS-staged, R14-verified depth-1 prefetch
// skeleton + START-TIME DE-PHASING:
//   All 1176 blocks are co-resident (5/CU x 256 CU = 1280 slots), start
//   simultaneously, and run an identical 16-iter barrier cadence -> the 5
//   blocks sharing a CU plausibly phase-lock: every wave on the CU hits its
//   vmcnt-drain window at the same moment, leaving nothing to hide it.
//   Fix attempt: stagger block start by hash(bid)%5 * ~1.4k cycles
//   (s_sleep chain) so one block's MFMA phase covers its neighbors' drains.
//   - tile 128x128, BK=128 fp4, 16 K-iters; LDS 2x(8+8) KiB = 32 KiB
//   - stage next K-tile before consuming current; ONE __syncthreads/iter
//   - swizzle: stage chunk ((l&3)^((row>>1)&3)) of the row's 64B window
//     (full-line coalescing); read slot l4^((lr>>1)&3) (conflict-free)
//   - mfma_scale_f32_16x16x128_f8f6f4 cbsz=blgp=4, scales 0x79 (exact /4096)
// XCD-aware triangular decode (1176 = 8 XCDs x 147 jobs, balanced).
__global__ __launch_bounds__(256) void simexp_kernel(
    const unsigned char* __restrict__ zb4, float* __restrict__ S)
{
    __shared__ unsigned char As[2][8192];
    __shared__ unsigned char Bs[2][8192];

    // de-phase: hash -> 0..4 phases, ~1408 cy apart (s_sleep 22 = 22*64 cy)
    {
        const unsigned int phase = (blockIdx.x * 2654435761u) >> 28;  // 0..15
        const unsigned int steps = phase % 5u;                        // 0..4
        for (unsigned int i = 0; i < steps; ++i) __builtin_amdgcn_s_sleep(22);
    }

    const int x  = blockIdx.x & 7;
    const int j  = blockIdx.x >> 3;
    const int pi = j / 49;
    const int jj = j % 49;
    const int p  = 3 * x + pi;
    int rt, ct;
    if (jj < 48 - p) { rt = p;      ct = p + jj; }
    else             { rt = 47 - p; ct = rt + (jj - (48 - p)); }

    const int tid  = threadIdx.x;
    const int lane = tid & 63;
    const int w    = tid >> 6;       // wave 0..3
    const int wr   = w >> 1, wc = w & 1;
    const int rowA0 = rt * 128, colB0 = ct * 128;

    const int rowc = lane >> 2;                               // 0..15
    const int csw  = (((lane & 3) ^ ((rowc >> 1) & 3))) * 16; // swizzled chunk (bytes)

    const int lr = lane & 15;
    const int l4 = lane >> 4;                                 // 0..3
    const int rsl = ((l4 ^ ((lr >> 1) & 3))) * 16;            // read slot (bytes)

    f32x4 acc[4][4] = {};

    // staging duty: wave w covers 16-row groups {2w, 2w+1} of A and B
#define STAGE(buf, kw) do {                                                  \
    _Pragma("unroll")                                                        \
    for (int g2 = 0; g2 < 2; ++g2) {                                         \
        const int g = w * 2 + g2;                                            \
        const unsigned char* ga = zb4                                        \
            + (size_t)(rowA0 + g*16 + rowc) * 1024 + (kw)*64 + csw;          \
        __builtin_amdgcn_global_load_lds(                                    \
            (const __attribute__((address_space(1))) void*)ga,               \
            (__attribute__((address_space(3))) void*)&As[buf][g * 1024],     \
            16, 0, 0);                                                       \
        const unsigned char* gb = zb4                                        \
            + (size_t)(colB0 + g*16 + rowc) * 1024 + (kw)*64 + csw;          \
        __builtin_amdgcn_global_load_lds(                                    \
            (const __attribute__((address_space(1))) void*)gb,               \
            (__attribute__((address_space(3))) void*)&Bs[buf][g * 1024],     \
            16, 0, 0);                                                       \
    }                                                                        \
} while (0)

    STAGE(0, 0);
    __syncthreads();

    for (int t = 0; t < 16; ++t) {
        const int cur = t & 1;
        if (t < 15) STAGE(cur ^ 1, t + 1);   // prefetch next K-tile

        i32x8 a8[4];
        #pragma unroll
        for (int mi = 0; mi < 4; ++mi) {
            i32x4 tv = *(const i32x4*)&As[cur][(wr*4 + mi)*1024 + lr*64 + rsl];
            a8[mi] = __builtin_shufflevector(tv, tv, 0, 1, 2, 3, -1, -1, -1, -1);
        }
        __builtin_amdgcn_s_setprio(1);
        #pragma unroll
        for (int ni = 0; ni < 4; ++ni) {
            i32x4 tv = *(const i32x4*)&Bs[cur][(wc*4 + ni)*1024 + lr*64 + rsl];
            i32x8 b8 = __builtin_shufflevector(tv, tv, 0, 1, 2, 3, -1, -1, -1, -1);
            #pragma unroll
            for (int mi = 0; mi < 4; ++mi)
                acc[mi][ni] = __builtin_amdgcn_mfma_scale_f32_16x16x128_f8f6f4(
                    a8[mi], b8, acc[mi][ni], 4, 4,
                    0, 0x79797979, 0, 0x79797979);
        }
        __builtin_amdgcn_s_setprio(0);

        if (t < 15) __syncthreads();   // drains vmcnt+lgkm: next buf ready,
                                       // current buf safe to overwrite
    }

    // exp in-register (reused for both row- and col-sums)
    #pragma unroll
    for (int mi = 0; mi < 4; ++mi)
        #pragma unroll
        for (int ni = 0; ni < 4; ++ni)
            #pragma unroll
            for (int q = 0; q < 4; ++q)
                acc[mi][ni][q] = __expf(10.0f * acc[mi][ni][q]);

    // ---- row-sums: C/D row = (lane>>4)*4 + q (+mi*16), col = lane&15 (+ni*16)
    {
        float rs[4][4];
        #pragma unroll
        for (int mi = 0; mi < 4; ++mi)
            #pragma unroll
            for (int q = 0; q < 4; ++q) {
                float s = 0.f;
                #pragma unroll
                for (int ni = 0; ni < 4; ++ni) s += acc[mi][ni][q];
                rs[mi][q] = s;
            }
        #pragma unroll
        for (int off = 1; off < 16; off <<= 1)
            #pragma unroll
            for (int mi = 0; mi < 4; ++mi)
                #pragma unroll
                for (int q = 0; q < 4; ++q)
                    rs[mi][q] += __shfl_xor(rs[mi][q], off, 64);

        if ((lane & 15) == 0) {
            float* St = S + ((ct < BIJ / 128) ? 0 : SIZE);
            int rq = l4 * 4;
            #pragma unroll
            for (int mi = 0; mi < 4; ++mi)
                #pragma unroll
                for (int q = 0; q < 4; ++q)
                    atomicAdd(&St[rowA0 + wr*64 + mi*16 + rq + q], rs[mi][q]);
        }
    }

    // ---- col-sums (transpose contribution), off-diagonal tiles only
    if (rt != ct) {
        float cs[4];
        #pragma unroll
        for (int ni = 0; ni < 4; ++ni) {
            float s = 0.f;
            #pragma unroll
            for (int mi = 0; mi < 4; ++mi)
                #pragma unroll
                for (int q = 0; q < 4; ++q) s += acc[mi][ni][q];
            cs[ni] = s;
        }
        #pragma unroll
        for (int off = 16; off < 64; off <<= 1)
            #pragma unroll
            for (int ni = 0; ni < 4; ++ni)
                cs[ni] += __shfl_xor(cs[ni], off, 64);

        if (lane < 16) {
            float* St = S + ((rt < BIJ / 128) ? 0 : SIZE);
            #pragma unroll
            for (int ni = 0; ni < 4; ++ni)
                atomicAdd(&St[colB0 + wc*64 + ni*16 + lane], cs[ni]);
        }
    }
}

// Single block: per-row loss terms, total, write scalar.
__global__ __launch_bounds__(256) void loss_kernel(
    const float* __restrict__ S, const float* __restrict__ dii,
    float* __restrict__ out)
{
    __shared__ float red[4];
    float local = 0.f;
    const float c1 = logf((float)(BIJ - 1));
    const float c2 = logf((float)(BHALF - 1));
    for (int r = threadIdx.x; r < SIZE; r += 256) {
        float s1 = S[r], s2 = S[SIZE + r];
        float eii = __expf(10.0f * dii[r]);
        float denom = s1 + s2 - eii;
        float num, c;
        if (r < BIJ) { num = s1 - eii; c = c1; }
        else         { num = s2 - eii; c = c2; }
        local += __logf(denom / num) + c;
    }
    float tot = block_reduce_sum(local, red);
    if (threadIdx.x == 0) out[0] = tot / (float)SIZE;
}

extern "C" void kernel_launch(void* const* d_in, const int* in_sizes, int n_in,
                              void* d_out, int out_size, void* d_ws, size_t ws_size,
                              hipStream_t stream) {
    const float* ei = (const float*)d_in[0];
    const float* ej = (const float*)d_in[1];
    const float* ek = (const float*)d_in[2];
    float* out = (float*)d_out;

    char* ws = (char*)d_ws;
    unsigned char* zb4 = (unsigned char*)ws;                     // 6144*1024 = 6291456 B
    float* dii = (float*)(ws + 6291456);                         // 24576 B
    float* S   = (float*)(ws + 6291456 + 24576);                 // 2*6144*4 = 49152 B

    normalize_kernel<<<dim3(SIZE), dim3(256), 0, stream>>>(ei, ej, ek, zb4, dii, S);
    simexp_kernel<<<dim3(NT * (NT + 1) / 2), dim3(256), 0, stream>>>(zb4, S);
    loss_kernel<<<dim3(1), dim3(256), 0, stream>>>(S, dii, out);
}